// Round 6
// baseline (1025.463 us; speedup 1.0000x reference)
//
#include <hip/hip_runtime.h>
#include <hip/hip_fp16.h>

#define N_NODES 100000
#define E_EDGES 1600000
#define F_IN    256
#define F_HID   64
#define F_OUT   16
#define NBKT    1563          // ceil(N/64): buckets of 64 dst nodes
#define PA_BLOCKS 98          // hist/passA blocks
#define PA_EDGES  16384       // edges per hist/passA block (98*16384 >= E)
#define GEMM1_BLOCKS 782      // ceil(N/128)
#define W1SW_BLOCKS  64

typedef _Float16 half8   __attribute__((ext_vector_type(8)));
typedef float    floatx4 __attribute__((ext_vector_type(4)));

// ---------------------------------------------------------------------------
// Prep (fused): blocks [0,64): swizzle W1 -> f16 MFMA B-frag order.
// Blocks [64,64+98): per-block LDS histogram over 1563 buckets (dst>>6),
// written as plain rows of counts[blk][NBKT] — no global atomics.
// ---------------------------------------------------------------------------
__global__ __launch_bounds__(256) void prep_kernel(const float* __restrict__ W1,
                                                   _Float16* __restrict__ w1sw,
                                                   const int* __restrict__ edst,
                                                   int* __restrict__ counts) {
    const int t = threadIdx.x;
    if (blockIdx.x < W1SW_BLOCKS) {
        const int i = blockIdx.x * 256 + t;   // 16384
        const int k = i >> 6, n = i & 63;
        const int kb = k >> 5, quad = (k >> 3) & 3, j = k & 7;
        const int nt = n >> 4, ln = n & 15;
        w1sw[((size_t)((kb * 4 + nt) * 64 + quad * 16 + ln)) * 8 + j] = (_Float16)W1[i];
        return;
    }
    __shared__ int hist[NBKT];
    const int blk = blockIdx.x - W1SW_BLOCKS;
    for (int i = t; i < NBKT; i += 256) hist[i] = 0;
    __syncthreads();
    const int base = blk * PA_EDGES;
#pragma unroll
    for (int i = 0; i < PA_EDGES / 1024; ++i) {
        const int e0 = base + (i * 256 + t) * 4;
        if (e0 < E_EDGES) {
            int4 d4 = *(const int4*)&edst[e0];
            atomicAdd(&hist[d4.x >> 6], 1);
            atomicAdd(&hist[d4.y >> 6], 1);
            atomicAdd(&hist[d4.z >> 6], 1);
            atomicAdd(&hist[d4.w >> 6], 1);
        }
    }
    __syncthreads();
    for (int i = t; i < NBKT; i += 256) counts[blk * NBKT + i] = hist[i];
}

// ---------------------------------------------------------------------------
// Column scan: for 16 buckets per block, exclusive prefix of counts over the
// 98 passA blocks -> colPrefix[blk][bkt]; column totals -> totals[bkt].
// ---------------------------------------------------------------------------
__global__ __launch_bounds__(256) void colscan_kernel(const int* __restrict__ counts,
                                                      int* __restrict__ colPrefix,
                                                      int* __restrict__ totals) {
    __shared__ int m[PA_BLOCKS][16];
    const int t = threadIdx.x;
    const int b0 = blockIdx.x * 16;
    for (int i = t; i < PA_BLOCKS * 16; i += 256) {
        const int r = i >> 4, c = i & 15, bkt = b0 + c;
        m[r][c] = (bkt < NBKT) ? counts[r * NBKT + bkt] : 0;
    }
    __syncthreads();
    if (t < 16) {
        int run = 0;
        for (int r = 0; r < PA_BLOCKS; ++r) { const int v = m[r][t]; m[r][t] = run; run += v; }
        if (b0 + t < NBKT) totals[b0 + t] = run;
    }
    __syncthreads();
    for (int i = t; i < PA_BLOCKS * 16; i += 256) {
        const int r = i >> 4, c = i & 15, bkt = b0 + c;
        if (bkt < NBKT) colPrefix[r * NBKT + bkt] = m[r][c];
    }
}

// ---------------------------------------------------------------------------
// Exclusive scan of 1563 bucket totals -> bucketStart[0..NBKT], sentinel = E.
// ---------------------------------------------------------------------------
__global__ __launch_bounds__(256) void scantot_kernel(const int* __restrict__ totals,
                                                      int* __restrict__ bucketStart) {
    __shared__ int s[256];
    const int t = threadIdx.x;
    const int base = t * 7;
    int v[7], sum = 0;
#pragma unroll
    for (int r = 0; r < 7; ++r) {
        v[r] = (base + r < NBKT) ? totals[base + r] : 0;
        sum += v[r];
    }
    s[t] = sum;
    __syncthreads();
#pragma unroll
    for (int off = 1; off < 256; off <<= 1) {
        const int y = (t >= off) ? s[t - off] : 0;
        __syncthreads();
        s[t] += y;
        __syncthreads();
    }
    int run = s[t] - sum;
#pragma unroll
    for (int r = 0; r < 7; ++r) {
        if (base + r < NBKT) bucketStart[base + r] = run;
        run += v[r];
    }
    if (t == 0) bucketStart[NBKT] = E_EDGES;
}

// ---------------------------------------------------------------------------
// K1 (fused): blocks [0,GEMM1_BLOCKS): support1 = x @ W1 via MFMA f16.
// Blocks after: passA — deterministic bucket scatter, cursor = bucketStart +
// colPrefix (no global atomics; rank via LDS ds_add_rtn only).
// ---------------------------------------------------------------------------
__global__ __launch_bounds__(256) void gemm1_passA_kernel(const float* __restrict__ x,
                                                          const _Float16* __restrict__ w1sw,
                                                          _Float16* __restrict__ support1,
                                                          const int* __restrict__ esrc,
                                                          const int* __restrict__ edst,
                                                          const float* __restrict__ evals,
                                                          const int* __restrict__ bucketStart,
                                                          const int* __restrict__ colPrefix,
                                                          int2* __restrict__ tmp) {
    __shared__ __align__(16) char ldsbuf[32768];
    const int t = threadIdx.x;

    if (blockIdx.x >= GEMM1_BLOCKS) {
        // ---- passA ----
        int* cur = (int*)ldsbuf;   // NBKT ints
        const int blk = blockIdx.x - GEMM1_BLOCKS;
        for (int i = t; i < NBKT; i += 256)
            cur[i] = bucketStart[i] + colPrefix[blk * NBKT + i];
        __syncthreads();
        const int base = blk * PA_EDGES;
#pragma unroll 2
        for (int i = 0; i < PA_EDGES / 1024; ++i) {
            const int e0 = base + (i * 256 + t) * 4;
            if (e0 < E_EDGES) {
                int4 d4 = *(const int4*)&edst[e0];
                int4 s4 = *(const int4*)&esrc[e0];
                float4 v4 = *(const float4*)&evals[e0];
                const int dd[4] = {d4.x, d4.y, d4.z, d4.w};
                const int ss[4] = {s4.x, s4.y, s4.z, s4.w};
                const float vv[4] = {v4.x, v4.y, v4.z, v4.w};
#pragma unroll
                for (int u = 0; u < 4; ++u) {
                    const int pos = atomicAdd(&cur[dd[u] >> 6], 1);
                    tmp[pos] = make_int2(((dd[u] & 63) << 17) | ss[u],
                                         __float_as_int(vv[u]));
                }
            }
        }
        return;
    }

    // ---- MFMA gemm1 ----
    _Float16* Bs = (_Float16*)ldsbuf;   // 32 KB, frag-ordered
    {
        const float4* srcv = (const float4*)w1sw;
        float4*       dstv = (float4*)Bs;
#pragma unroll
        for (int i = 0; i < 8; ++i) dstv[t + i * 256] = srcv[t + i * 256];
    }
    __syncthreads();

    const int wave = t >> 6;
    const int lane = t & 63;
    const int ln   = lane & 15;
    const int quad = lane >> 4;
    const int row0 = blockIdx.x * 128 + wave * 32;

    const float* xp[2];
#pragma unroll
    for (int mt = 0; mt < 2; ++mt) {
        int r = row0 + mt * 16 + ln;
        if (r > N_NODES - 1) r = N_NODES - 1;
        xp[mt] = x + (size_t)r * F_IN + quad * 8;
    }

    floatx4 acc[2][4] = {};

#pragma unroll 4
    for (int kb = 0; kb < 8; ++kb) {
        half8 a[2];
#pragma unroll
        for (int mt = 0; mt < 2; ++mt) {
            float4 v0 = *(const float4*)(xp[mt] + kb * 32);
            float4 v1 = *(const float4*)(xp[mt] + kb * 32 + 4);
            half8 h;
            h[0] = (_Float16)v0.x; h[1] = (_Float16)v0.y;
            h[2] = (_Float16)v0.z; h[3] = (_Float16)v0.w;
            h[4] = (_Float16)v1.x; h[5] = (_Float16)v1.y;
            h[6] = (_Float16)v1.z; h[7] = (_Float16)v1.w;
            a[mt] = h;
        }
#pragma unroll
        for (int nt = 0; nt < 4; ++nt) {
            half8 b = *(const half8*)&Bs[((size_t)((kb * 4 + nt) * 64 + lane)) * 8];
            acc[0][nt] = __builtin_amdgcn_mfma_f32_16x16x32_f16(a[0], b, acc[0][nt], 0, 0, 0);
            acc[1][nt] = __builtin_amdgcn_mfma_f32_16x16x32_f16(a[1], b, acc[1][nt], 0, 0, 0);
        }
    }

#pragma unroll
    for (int mt = 0; mt < 2; ++mt) {
        const int rbase = row0 + mt * 16 + quad * 4;
#pragma unroll
        for (int r = 0; r < 4; ++r) {
            const int row = rbase + r;
            if (row < N_NODES) {
#pragma unroll
                for (int nt = 0; nt < 4; ++nt)
                    support1[(size_t)row * F_HID + nt * 16 + ln] = (_Float16)acc[mt][nt][r];
            }
        }
    }
}

// ---------------------------------------------------------------------------
// K2: one block per 64-node bucket. LDS fp32 h accumulation via ds_add_f32
// (order-free -> no per-node CSR needed). Feature-pair dword gathers: lanes
// 0-31 edge A, 32-63 edge B; lane adds features (2c -> slot c, 2c+1 -> slot
// 32+c) — parity-split layout keeps ds_add at free 2-way bank aliasing.
// Epilogue: support2 = relu(h+b1) @ W2 (f16).
// ---------------------------------------------------------------------------
__global__ __launch_bounds__(256) void spmm1_bucket_kernel(const int* __restrict__ bucketStart,
                                                           const int2* __restrict__ tmp,
                                                           const _Float16* __restrict__ support1,
                                                           const float* __restrict__ b1,
                                                           const float* __restrict__ W2,
                                                           _Float16* __restrict__ support2) {
    __shared__ float h[64 * 64];
    __shared__ float W2s[64 * 16];
    __shared__ float b1s[64];
    const int t = threadIdx.x;
#pragma unroll
    for (int i = 0; i < 16; ++i) h[t + i * 256] = 0.f;
    for (int i = t; i < 1024; i += 256) {
        const int slot = i >> 4, j = i & 15;
        const int f = (slot < 32) ? (2 * slot) : (2 * (slot - 32) + 1);
        W2s[i] = W2[f * 16 + j];
    }
    if (t < 64) {
        const int f = (t < 32) ? (2 * t) : (2 * (t - 32) + 1);
        b1s[t] = b1[f];
    }
    const int beg = bucketStart[blockIdx.x];
    const int end = bucketStart[blockIdx.x + 1];
    __syncthreads();

    const int wave = t >> 6, lane = t & 63;
    const int c = lane & 31, p = lane >> 5;

    for (int base = beg + wave * 64; base < end; base += 256) {
        const int rem = end - base;
        const int lim = rem < 64 ? rem : 64;
        int ri = 0, rv = 0;
        if (lane < lim) { int2 r = tmp[base + lane]; ri = r.x; rv = r.y; }
        const int pairs = (lim + 1) >> 1;
        int k = 0;
        for (; k + 4 <= pairs; k += 4) {
            unsigned f2[4]; float wv[4]; int dl[4];
#pragma unroll
            for (int u = 0; u < 4; ++u) {
                const int idx = 2 * (k + u) + p;
                int r_i = __shfl(ri, idx);
                int r_v = __shfl(rv, idx);
                if (idx >= lim) { r_i = 0; r_v = 0; }
                dl[u] = r_i >> 17;
                const int s = r_i & 0x1FFFF;
                f2[u] = *(const unsigned*)&support1[(size_t)s * F_HID + 2 * c];
                wv[u] = __int_as_float(r_v);
            }
#pragma unroll
            for (int u = 0; u < 4; ++u) {
                const _Float16* hp = (const _Float16*)&f2[u];
                atomicAdd(&h[dl[u] * 64 + c],      wv[u] * (float)hp[0]);
                atomicAdd(&h[dl[u] * 64 + 32 + c], wv[u] * (float)hp[1]);
            }
        }
        for (; k < pairs; ++k) {
            const int idx = 2 * k + p;
            int r_i = __shfl(ri, idx);
            int r_v = __shfl(rv, idx);
            if (idx >= lim) { r_i = 0; r_v = 0; }
            const int dl = r_i >> 17;
            const int s = r_i & 0x1FFFF;
            const unsigned f2 = *(const unsigned*)&support1[(size_t)s * F_HID + 2 * c];
            const float w = __int_as_float(r_v);
            const _Float16* hp = (const _Float16*)&f2;
            atomicAdd(&h[dl * 64 + c],      w * (float)hp[0]);
            atomicAdd(&h[dl * 64 + 32 + c], w * (float)hp[1]);
        }
    }
    __syncthreads();

    // Epilogue: thread (n = t>>2, q = t&3) covers slots q*16..q*16+15.
    const int n = t >> 2, q = t & 3;
    float acc[16];
#pragma unroll
    for (int j = 0; j < 16; ++j) acc[j] = 0.f;
#pragma unroll
    for (int kk = 0; kk < 16; ++kk) {
        const int slot = q * 16 + kk;
        const float hv = fmaxf(h[n * 64 + slot] + b1s[slot], 0.f);
#pragma unroll
        for (int j = 0; j < 16; ++j) acc[j] = fmaf(hv, W2s[slot * 16 + j], acc[j]);
    }
#pragma unroll
    for (int j = 0; j < 16; ++j) {
        acc[j] += __shfl_xor(acc[j], 1);
        acc[j] += __shfl_xor(acc[j], 2);
    }
    const int node = blockIdx.x * 64 + n;
    if (node < N_NODES) {
        _Float16 o4[4];
#pragma unroll
        for (int j = 0; j < 4; ++j) o4[j] = (_Float16)acc[q * 4 + j];
        *(uint2*)&support2[(size_t)node * F_OUT + q * 4] = *(const uint2*)o4;
    }
}

// ---------------------------------------------------------------------------
// K3: one block per 64-node bucket. 8 edges per wave-instr (8 lanes/edge,
// 2 features/lane). LDS h2 parity-split (2c -> slot c, 2c+1 -> slot 8+c).
// Epilogue: +b2, log_softmax, write out.
// ---------------------------------------------------------------------------
__global__ __launch_bounds__(256) void spmm2_bucket_kernel(const int* __restrict__ bucketStart,
                                                           const int2* __restrict__ tmp,
                                                           const _Float16* __restrict__ support2,
                                                           const float* __restrict__ b2,
                                                           float* __restrict__ out) {
    __shared__ float h2[64 * 16];
    __shared__ float b2s[16];
    const int t = threadIdx.x;
#pragma unroll
    for (int i = 0; i < 4; ++i) h2[t + i * 256] = 0.f;
    if (t < 16) b2s[t] = b2[t];
    const int beg = bucketStart[blockIdx.x];
    const int end = bucketStart[blockIdx.x + 1];
    __syncthreads();

    const int wave = t >> 6, lane = t & 63;
    const int c = lane & 7, e8 = lane >> 3;

    for (int base = beg + wave * 64; base < end; base += 256) {
        const int rem = end - base;
        const int lim = rem < 64 ? rem : 64;
        int ri = 0, rv = 0;
        if (lane < lim) { int2 r = tmp[base + lane]; ri = r.x; rv = r.y; }
        const int oct = (lim + 7) >> 3;
        int k = 0;
        for (; k + 4 <= oct; k += 4) {
            unsigned f2[4]; float wv[4]; int dl[4];
#pragma unroll
            for (int u = 0; u < 4; ++u) {
                const int idx = 8 * (k + u) + e8;
                int r_i = __shfl(ri, idx);
                int r_v = __shfl(rv, idx);
                if (idx >= lim) { r_i = 0; r_v = 0; }
                dl[u] = r_i >> 17;
                const int s = r_i & 0x1FFFF;
                f2[u] = *(const unsigned*)&support2[(size_t)s * F_OUT + 2 * c];
                wv[u] = __int_as_float(r_v);
            }
#pragma unroll
            for (int u = 0; u < 4; ++u) {
                const _Float16* hp = (const _Float16*)&f2[u];
                atomicAdd(&h2[dl[u] * 16 + c],     wv[u] * (float)hp[0]);
                atomicAdd(&h2[dl[u] * 16 + 8 + c], wv[u] * (float)hp[1]);
            }
        }
        for (; k < oct; ++k) {
            const int idx = 8 * k + e8;
            int r_i = __shfl(ri, idx);
            int r_v = __shfl(rv, idx);
            if (idx >= lim) { r_i = 0; r_v = 0; }
            const int dl = r_i >> 17;
            const int s = r_i & 0x1FFFF;
            const unsigned f2 = *(const unsigned*)&support2[(size_t)s * F_OUT + 2 * c];
            const float w = __int_as_float(r_v);
            const _Float16* hp = (const _Float16*)&f2;
            atomicAdd(&h2[dl * 16 + c],     w * (float)hp[0]);
            atomicAdd(&h2[dl * 16 + 8 + c], w * (float)hp[1]);
        }
    }
    __syncthreads();

    const int j = t & 15, g = t >> 4;
    const int slot = (j & 1) ? (8 + (j >> 1)) : (j >> 1);   // feature j's LDS slot
#pragma unroll
    for (int r = 0; r < 4; ++r) {
        const int n = g + r * 16;
        const int node = blockIdx.x * 64 + n;
        const float v = h2[n * 16 + slot] + b2s[j];
        float m = v;
#pragma unroll
        for (int off = 8; off > 0; off >>= 1)
            m = fmaxf(m, __shfl_xor(m, off, 16));
        const float ex = __expf(v - m);
        float sum = ex;
#pragma unroll
        for (int off = 8; off > 0; off >>= 1)
            sum += __shfl_xor(sum, off, 16);
        if (node < N_NODES)
            out[(size_t)node * F_OUT + j] = v - m - __logf(sum);
    }
}

// ---------------------------------------------------------------------------
extern "C" void kernel_launch(void* const* d_in, const int* in_sizes, int n_in,
                              void* d_out, int out_size, void* d_ws, size_t ws_size,
                              hipStream_t stream) {
    const float* x     = (const float*)d_in[0];
    const int*   esrc  = (const int*)  d_in[1];
    const int*   edst  = (const int*)  d_in[2];
    const float* evals = (const float*)d_in[3];
    const float* W1    = (const float*)d_in[4];
    const float* b1    = (const float*)d_in[5];
    const float* W2    = (const float*)d_in[6];
    const float* b2    = (const float*)d_in[7];
    float* out = (float*)d_out;

    // Workspace layout (~30.1 MB), 16 B-aligned segments.
    char* ws = (char*)d_ws;
    _Float16* support1    = (_Float16*)(ws);              // 12,800,000 B
    _Float16* support2    = (_Float16*)(ws + 12800000);   //  3,200,000 B
    int2*     tmp         = (int2*)    (ws + 16000000);   // 12,800,000 B
    int*      counts      = (int*)     (ws + 28800000);   //    612,696 B (98*1563*4)
    int*      colPrefix   = (int*)     (ws + 29412800);   //    612,696 B
    int*      totals      = (int*)     (ws + 30025600);   //      6,256 B
    int*      bucketStart = (int*)     (ws + 30032000);   //      6,256 B
    _Float16* w1sw        = (_Float16*)(ws + 30038272);   //     32,768 B

    prep_kernel<<<W1SW_BLOCKS + PA_BLOCKS, 256, 0, stream>>>(W1, w1sw, edst, counts);
    colscan_kernel<<<PA_BLOCKS, 256, 0, stream>>>(counts, colPrefix, totals);
    scantot_kernel<<<1, 256, 0, stream>>>(totals, bucketStart);
    gemm1_passA_kernel<<<GEMM1_BLOCKS + PA_BLOCKS, 256, 0, stream>>>(
        x, w1sw, support1, esrc, edst, evals, bucketStart, colPrefix, tmp);
    spmm1_bucket_kernel<<<NBKT, 256, 0, stream>>>(bucketStart, tmp, support1, b1, W2, support2);
    spmm2_bucket_kernel<<<NBKT, 256, 0, stream>>>(bucketStart, tmp, support2, b2, out);
}

// Round 7
// 335.522 us; speedup vs baseline: 3.0563x; 3.0563x over previous
//
#include <hip/hip_runtime.h>
#include <hip/hip_fp16.h>

#define N_NODES 100000
#define E_EDGES 1600000
#define F_IN    256
#define F_HID   64
#define F_OUT   16
#define NBKT    98            // buckets of 1024 dst-nodes
#define W1SW_BLOCKS  64
#define AHIST_BLOCKS 1563     // ceil(E/1024)
#define GEMM1_BLOCKS 782      // ceil(N/128)

typedef _Float16 half8   __attribute__((ext_vector_type(8)));
typedef float    floatx4 __attribute__((ext_vector_type(4)));

// ---------------------------------------------------------------------------
// Prep (fused): blocks [0,64): swizzle W1 -> f16 MFMA B-frag order.
// blocks [64,..): coarse bucket histogram of edge dst (LDS hist, 98 global
// atomics per 1024-edge block).
// ---------------------------------------------------------------------------
__global__ __launch_bounds__(256) void prep_kernel(const float* __restrict__ W1,
                                                   _Float16* __restrict__ w1sw,
                                                   const int* __restrict__ edst,
                                                   int* __restrict__ bucketCount) {
    const int t = threadIdx.x;
    if (blockIdx.x < W1SW_BLOCKS) {
        const int i = blockIdx.x * 256 + t;   // 16384
        const int k = i >> 6, n = i & 63;
        const int kb = k >> 5, quad = (k >> 3) & 3, j = k & 7;
        const int nt = n >> 4, ln = n & 15;
        w1sw[((size_t)((kb * 4 + nt) * 64 + quad * 16 + ln)) * 8 + j] = (_Float16)W1[i];
        return;
    }
    __shared__ int hist[128];
    const int blk = blockIdx.x - W1SW_BLOCKS;
    if (t < NBKT) hist[t] = 0;
    __syncthreads();
    const int e0 = blk * 1024 + t * 4;
    if (e0 < E_EDGES) {
        int4 d4 = *(const int4*)&edst[e0];
        atomicAdd(&hist[d4.x >> 10], 1);
        atomicAdd(&hist[d4.y >> 10], 1);
        atomicAdd(&hist[d4.z >> 10], 1);
        atomicAdd(&hist[d4.w >> 10], 1);
    }
    __syncthreads();
    if (t < NBKT) atomicAdd(&bucketCount[t], hist[t]);
}

// ---------------------------------------------------------------------------
// Exclusive scan of 98 bucket counts -> bucketStart; init bucketCursor.
// ---------------------------------------------------------------------------
__global__ __launch_bounds__(128) void bucket_scan_kernel(const int* __restrict__ bucketCount,
                                                          int* __restrict__ bucketStart,
                                                          int* __restrict__ bucketCursor) {
    __shared__ int s[128];
    const int t = threadIdx.x;
    int v = (t < NBKT) ? bucketCount[t] : 0;
    s[t] = v;
    __syncthreads();
#pragma unroll
    for (int off = 1; off < 128; off <<= 1) {
        int y = (t >= off) ? s[t - off] : 0;
        __syncthreads();
        s[t] += y;
        __syncthreads();
    }
    if (t < NBKT) { bucketStart[t] = s[t] - v; bucketCursor[t] = s[t] - v; }
}

// ---------------------------------------------------------------------------
// K1 (fused): blocks [0,GEMM1_BLOCKS): support1 = x @ W1 via MFMA f16.
// Blocks after that: pass A of the bucket sort — write packed records
// (dstLocal<<17 | src, val) into bucket regions (dense, L2-friendly).
// ---------------------------------------------------------------------------
__global__ __launch_bounds__(256) void gemm1_passA_kernel(const float* __restrict__ x,
                                                          const _Float16* __restrict__ w1sw,
                                                          _Float16* __restrict__ support1,
                                                          const int* __restrict__ esrc,
                                                          const int* __restrict__ edst,
                                                          const float* __restrict__ evals,
                                                          int* __restrict__ bucketCursor,
                                                          int2* __restrict__ tmp) {
    __shared__ __align__(16) char ldsbuf[32768];
    const int t = threadIdx.x;

    if (blockIdx.x >= GEMM1_BLOCKS) {
        // ---- pass A ----
        int* hist = (int*)ldsbuf;          // 128 ints
        int* base = (int*)ldsbuf + 128;    // 128 ints
        const int blk = blockIdx.x - GEMM1_BLOCKS;
        if (t < NBKT) hist[t] = 0;
        __syncthreads();
        const int e0 = blk * 1024 + t * 4;
        const bool ok = e0 < E_EDGES;
        int dd[4], ss[4], bu[4], rk[4];
        float vv[4];
        if (ok) {
            int4 d4 = *(const int4*)&edst[e0];
            int4 s4 = *(const int4*)&esrc[e0];
            float4 v4 = *(const float4*)&evals[e0];
            dd[0] = d4.x; dd[1] = d4.y; dd[2] = d4.z; dd[3] = d4.w;
            ss[0] = s4.x; ss[1] = s4.y; ss[2] = s4.z; ss[3] = s4.w;
            vv[0] = v4.x; vv[1] = v4.y; vv[2] = v4.z; vv[3] = v4.w;
#pragma unroll
            for (int u = 0; u < 4; ++u) {
                bu[u] = dd[u] >> 10;
                rk[u] = atomicAdd(&hist[bu[u]], 1);
            }
        }
        __syncthreads();
        if (t < NBKT) base[t] = atomicAdd(&bucketCursor[t], hist[t]);
        __syncthreads();
        if (ok) {
#pragma unroll
            for (int u = 0; u < 4; ++u) {
                int pos = base[bu[u]] + rk[u];
                tmp[pos] = make_int2(((dd[u] & 1023) << 17) | ss[u],
                                     __float_as_int(vv[u]));
            }
        }
        return;
    }

    // ---- MFMA gemm1 ----
    _Float16* Bs = (_Float16*)ldsbuf;   // 32 KB, frag-ordered
    {
        const float4* srcv = (const float4*)w1sw;
        float4*       dstv = (float4*)Bs;
#pragma unroll
        for (int i = 0; i < 8; ++i) dstv[t + i * 256] = srcv[t + i * 256];
    }
    __syncthreads();

    const int wave = t >> 6;
    const int lane = t & 63;
    const int ln   = lane & 15;
    const int quad = lane >> 4;
    const int row0 = blockIdx.x * 128 + wave * 32;

    const float* xp[2];
#pragma unroll
    for (int mt = 0; mt < 2; ++mt) {
        int r = row0 + mt * 16 + ln;
        if (r > N_NODES - 1) r = N_NODES - 1;
        xp[mt] = x + (size_t)r * F_IN + quad * 8;
    }

    floatx4 acc[2][4] = {};

#pragma unroll 4
    for (int kb = 0; kb < 8; ++kb) {
        half8 a[2];
#pragma unroll
        for (int mt = 0; mt < 2; ++mt) {
            float4 v0 = *(const float4*)(xp[mt] + kb * 32);
            float4 v1 = *(const float4*)(xp[mt] + kb * 32 + 4);
            half8 h;
            h[0] = (_Float16)v0.x; h[1] = (_Float16)v0.y;
            h[2] = (_Float16)v0.z; h[3] = (_Float16)v0.w;
            h[4] = (_Float16)v1.x; h[5] = (_Float16)v1.y;
            h[6] = (_Float16)v1.z; h[7] = (_Float16)v1.w;
            a[mt] = h;
        }
#pragma unroll
        for (int nt = 0; nt < 4; ++nt) {
            half8 b = *(const half8*)&Bs[((size_t)((kb * 4 + nt) * 64 + lane)) * 8];
            acc[0][nt] = __builtin_amdgcn_mfma_f32_16x16x32_f16(a[0], b, acc[0][nt], 0, 0, 0);
            acc[1][nt] = __builtin_amdgcn_mfma_f32_16x16x32_f16(a[1], b, acc[1][nt], 0, 0, 0);
        }
    }

#pragma unroll
    for (int mt = 0; mt < 2; ++mt) {
        const int rbase = row0 + mt * 16 + quad * 4;
#pragma unroll
        for (int r = 0; r < 4; ++r) {
            const int row = rbase + r;
            if (row < N_NODES) {
#pragma unroll
                for (int nt = 0; nt < 4; ++nt)
                    support1[(size_t)row * F_HID + nt * 16 + ln] = (_Float16)acc[mt][nt][r];
            }
        }
    }
}

// ---------------------------------------------------------------------------
// Pass B: one block per bucket. LDS degree hist + scan + cursors; final
// scatter within a ~131 KB L2-resident window. Emits rowstart/deg directly.
// ---------------------------------------------------------------------------
__global__ __launch_bounds__(256) void passB_kernel(const int2* __restrict__ tmp,
                                                    const int* __restrict__ bucketStart,
                                                    const int* __restrict__ bucketCount,
                                                    int2* __restrict__ sorted_edges,
                                                    int* __restrict__ rowstart,
                                                    int* __restrict__ deg) {
    __shared__ int ldeg[1024];
    __shared__ int lcur[1024];
    __shared__ int s[256];
    const int t = threadIdx.x;
    const int b = blockIdx.x;
    const int node0 = b << 10;
    const int beg = bucketStart[b];
    const int cnt = bucketCount[b];

#pragma unroll
    for (int i = 0; i < 4; ++i) ldeg[t + i * 256] = 0;
    __syncthreads();

    for (int p = beg + t; p < beg + cnt; p += 256) {
        int2 r = tmp[p];
        atomicAdd(&ldeg[r.x >> 17], 1);
    }
    __syncthreads();

    int v[4], sum = 0;
#pragma unroll
    for (int r = 0; r < 4; ++r) { v[r] = ldeg[t * 4 + r]; sum += v[r]; }
    s[t] = sum;
    __syncthreads();
#pragma unroll
    for (int off = 1; off < 256; off <<= 1) {
        int y = (t >= off) ? s[t - off] : 0;
        __syncthreads();
        s[t] += y;
        __syncthreads();
    }
    int run = s[t] - sum;
#pragma unroll
    for (int r = 0; r < 4; ++r) {
        const int i = t * 4 + r;
        lcur[i] = run;
        const int node = node0 + i;
        if (node < N_NODES) { rowstart[node] = beg + run; deg[node] = v[r]; }
        run += v[r];
    }
    __syncthreads();

    for (int p = beg + t; p < beg + cnt; p += 256) {
        int2 r = tmp[p];
        const int dl  = r.x >> 17;
        const int pos = beg + atomicAdd(&lcur[dl], 1);
        sorted_edges[pos] = make_int2(r.x & 0x1FFFF, r.y);
    }
}

// ---------------------------------------------------------------------------
// K2 fused: per dst node (one wave): h = relu(sum_e w*support1[src] + b1),
// support2[node] = h @ W2 (f16 out).
// Pair-gather: lane (p = lane>>5, c = lane&31) handles edges 2k+p, loading a
// dword (features 2c,2c+1) per edge — halves bpermute+load count vs R5.
// Parity combine via shfl_xor(32). W2s padded stride 17 (no bank conflicts).
// ---------------------------------------------------------------------------
__global__ __launch_bounds__(256) void spmm1_fused_kernel(const int* __restrict__ rowstart,
                                                          const int* __restrict__ deg,
                                                          const int2* __restrict__ sorted_edges,
                                                          const _Float16* __restrict__ support1,
                                                          const float* __restrict__ b1,
                                                          const float* __restrict__ W2,
                                                          _Float16* __restrict__ support2) {
    __shared__ float W2s[64 * 17];   // padded: W2s[k*17+j]
    __shared__ float b1s[64];
    __shared__ float hs[4][64];
    const int t = threadIdx.x;
    for (int i = t; i < 1024; i += 256)
        W2s[(i >> 4) * 17 + (i & 15)] = W2[i];
    if (t < 64) b1s[t] = b1[t];
    __syncthreads();

    const int wave = t >> 6;
    const int lane = t & 63;
    const int node = blockIdx.x * 4 + wave;   // grid exact: 25000*4
    const int c = lane & 31;
    const int p = lane >> 5;

    const int beg = rowstart[node];
    const int cnt = deg[node];

    int   src_l = 0;
    float val_l = 0.f;
    if (lane < cnt) {
        int2 ev = sorted_edges[beg + lane];
        src_l = ev.x;
        val_l = __int_as_float(ev.y);
    }

    float acc0 = 0.f, acc1 = 0.f;
    const int kmax  = cnt < 64 ? cnt : 64;
    const int kp    = (((kmax + 1) >> 1) + 7) & ~7;   // pair-iters, 8-batched
    for (int k = 0; k < kp; k += 8) {
        float w[8], f0[8], f1[8];
#pragma unroll
        for (int u = 0; u < 8; ++u) {
            const int idx = 2 * (k + u) + p;          // <= 63
            const int s2  = __shfl(src_l, idx);       // 0 / w=0 beyond cnt
            w[u] = __shfl(val_l, idx);
            const unsigned d = *(const unsigned*)&support1[(size_t)s2 * F_HID + 2 * c];
            const _Float16* hp = (const _Float16*)&d;
            f0[u] = (float)hp[0];
            f1[u] = (float)hp[1];
        }
#pragma unroll
        for (int u = 0; u < 8; ++u) {
            acc0 = fmaf(w[u], f0[u], acc0);
            acc1 = fmaf(w[u], f1[u], acc1);
        }
    }
    for (int k = 64 + p; k < cnt; k += 2) {           // rare tail, parity-split
        int2 ev = sorted_edges[beg + k];
        const float w = __int_as_float(ev.y);
        const unsigned d = *(const unsigned*)&support1[(size_t)ev.x * F_HID + 2 * c];
        const _Float16* hp = (const _Float16*)&d;
        acc0 = fmaf(w, (float)hp[0], acc0);
        acc1 = fmaf(w, (float)hp[1], acc1);
    }

    acc0 += __shfl_xor(acc0, 32);
    acc1 += __shfl_xor(acc1, 32);
    if (p == 0) {
        float2 hv;
        hv.x = fmaxf(acc0 + b1s[2 * c],     0.f);
        hv.y = fmaxf(acc1 + b1s[2 * c + 1], 0.f);
        *(float2*)&hs[wave][2 * c] = hv;
    }
    __syncthreads();

    // Epilogue h @ W2: quad covers k-segment, reduce across quads.
    const int ln   = lane & 15;
    const int quad = lane >> 4;
    float o = 0.f;
#pragma unroll
    for (int kk = 0; kk < 16; ++kk) {
        const int k2 = quad * 16 + kk;
        o = fmaf(hs[wave][k2], W2s[k2 * 17 + ln], o);
    }
    o += __shfl_xor(o, 16);
    o += __shfl_xor(o, 32);
    if (quad == 0)
        support2[(size_t)node * F_OUT + ln] = (_Float16)o;
}

// ---------------------------------------------------------------------------
// K3 fused: per dst node (16 lanes): logits = sum_e w*support2[src] + b2,
// then log_softmax.  Pair-gather at width 16: lane (p=j>>3, c=j&7) handles
// edges 2k+p, dword loads (features 2c,2c+1); combine via shfl_xor(8,16).
// ---------------------------------------------------------------------------
__global__ __launch_bounds__(256) void spmm2_fused_kernel(const int* __restrict__ rowstart,
                                                          const int* __restrict__ deg,
                                                          const int2* __restrict__ sorted_edges,
                                                          const _Float16* __restrict__ support2,
                                                          const float* __restrict__ b2,
                                                          float* __restrict__ out) {
    __shared__ float b2s[16];
    const int t = threadIdx.x;
    if (t < 16) b2s[t] = b2[t];
    __syncthreads();

    const int j    = t & 15;
    const int node = blockIdx.x * 16 + (t >> 4);   // grid exact: 6250*16
    const int c = j & 7;
    const int p = j >> 3;

    const int beg = rowstart[node];
    const int cnt = deg[node];

    int   src_a = 0, src_b = 0;
    float val_a = 0.f, val_b = 0.f;
    if (j < cnt)      { int2 ev = sorted_edges[beg + j];      src_a = ev.x; val_a = __int_as_float(ev.y); }
    if (j + 16 < cnt) { int2 ev = sorted_edges[beg + 16 + j]; src_b = ev.x; val_b = __int_as_float(ev.y); }

    float acc0 = 0.f, acc1 = 0.f;
    {   // batch 1: edges 0..15 (8 pair-iters; w=0 beyond cnt)
        float w[8], f0[8], f1[8];
#pragma unroll
        for (int u = 0; u < 8; ++u) {
            const int idx = 2 * u + p;
            const int s2  = __shfl(src_a, idx, 16);
            w[u] = __shfl(val_a, idx, 16);
            const unsigned d = *(const unsigned*)&support2[(size_t)s2 * F_OUT + 2 * c];
            const _Float16* hp = (const _Float16*)&d;
            f0[u] = (float)hp[0];
            f1[u] = (float)hp[1];
        }
#pragma unroll
        for (int u = 0; u < 8; ++u) {
            acc0 = fmaf(w[u], f0[u], acc0);
            acc1 = fmaf(w[u], f1[u], acc1);
        }
    }
    if (cnt > 16) {   // batch 2: edges 16..31
        float w[8], f0[8], f1[8];
#pragma unroll
        for (int u = 0; u < 8; ++u) {
            const int idx = 2 * u + p;
            const int s2  = __shfl(src_b, idx, 16);
            w[u] = __shfl(val_b, idx, 16);
            const unsigned d = *(const unsigned*)&support2[(size_t)s2 * F_OUT + 2 * c];
            const _Float16* hp = (const _Float16*)&d;
            f0[u] = (float)hp[0];
            f1[u] = (float)hp[1];
        }
#pragma unroll
        for (int u = 0; u < 8; ++u) {
            acc0 = fmaf(w[u], f0[u], acc0);
            acc1 = fmaf(w[u], f1[u], acc1);
        }
    }
    for (int k = 32 + p; k < cnt; k += 2) {   // rare tail, parity-split
        int2 ev = sorted_edges[beg + k];
        const float w = __int_as_float(ev.y);
        const unsigned d = *(const unsigned*)&support2[(size_t)ev.x * F_OUT + 2 * c];
        const _Float16* hp = (const _Float16*)&d;
        acc0 = fmaf(w, (float)hp[0], acc0);
        acc1 = fmaf(w, (float)hp[1], acc1);
    }

    acc0 += __shfl_xor(acc0, 8, 16);
    acc1 += __shfl_xor(acc1, 8, 16);

    const float v0 = acc0 + b2s[2 * c];
    const float v1 = acc1 + b2s[2 * c + 1];
    float m = fmaxf(v0, v1);
#pragma unroll
    for (int off = 4; off > 0; off >>= 1)
        m = fmaxf(m, __shfl_xor(m, off, 16));
    float sum = __expf(v0 - m) + __expf(v1 - m);
#pragma unroll
    for (int off = 4; off > 0; off >>= 1)
        sum += __shfl_xor(sum, off, 16);
    if (p == 0) {
        const float lse = m + __logf(sum);
        float2 o = make_float2(v0 - lse, v1 - lse);
        *(float2*)&out[(size_t)node * F_OUT + 2 * c] = o;
    }
}

// ---------------------------------------------------------------------------
extern "C" void kernel_launch(void* const* d_in, const int* in_sizes, int n_in,
                              void* d_out, int out_size, void* d_ws, size_t ws_size,
                              hipStream_t stream) {
    const float* x     = (const float*)d_in[0];
    const int*   esrc  = (const int*)  d_in[1];
    const int*   edst  = (const int*)  d_in[2];
    const float* evals = (const float*)d_in[3];
    const float* W1    = (const float*)d_in[4];
    const float* b1    = (const float*)d_in[5];
    const float* W2    = (const float*)d_in[6];
    const float* b2    = (const float*)d_in[7];
    float* out = (float*)d_out;

    // Workspace layout (~42.5 MB); all segments 16 B-aligned.
    _Float16* support1     = (_Float16*)d_ws;                              // N*64 f16
    _Float16* support2     = support1 + (size_t)N_NODES * F_HID;           // N*16 f16
    int2*     tmp          = (int2*)(support2 + (size_t)N_NODES * F_OUT);  // E int2
    int2*     sorted_edges = tmp + E_EDGES;                                // E int2
    int*      rowstart     = (int*)(sorted_edges + E_EDGES);               // N
    int*      deg          = rowstart + N_NODES;                           // N
    int*      bucketCount  = deg + N_NODES;                                // 128
    int*      bucketStart  = bucketCount + 128;                            // 128
    int*      bucketCursor = bucketStart + 128;                            // 128
    _Float16* w1sw         = (_Float16*)(bucketCursor + 128);              // 16384 f16

    hipMemsetAsync(bucketCount, 0, 128 * sizeof(int), stream);
    prep_kernel<<<W1SW_BLOCKS + AHIST_BLOCKS, 256, 0, stream>>>(W1, w1sw, edst, bucketCount);
    bucket_scan_kernel<<<1, 128, 0, stream>>>(bucketCount, bucketStart, bucketCursor);
    gemm1_passA_kernel<<<GEMM1_BLOCKS + AHIST_BLOCKS, 256, 0, stream>>>(
        x, w1sw, support1, esrc, edst, evals, bucketCursor, tmp);
    passB_kernel<<<NBKT, 256, 0, stream>>>(tmp, bucketStart, bucketCount,
                                           sorted_edges, rowstart, deg);
    spmm1_fused_kernel<<<N_NODES / 4, 256, 0, stream>>>(rowstart, deg, sorted_edges,
                                                        support1, b1, W2, support2);
    spmm2_fused_kernel<<<N_NODES / 16, 256, 0, stream>>>(rowstart, deg, sorted_edges,
                                                         support2, b2, out);
}